// Round 5
// baseline (286.566 us; speedup 1.0000x reference)
//
#include <hip/hip_runtime.h>
#include <math.h>

#define NROWS 4096
#define NCOLS 32000
#define NC4   8000   // NCOLS / 4

// Single fused kernel, 4097 blocks:
//   block 0        : rt transform (histogram order-statistic selection),
//                    then spin-waits on a ticket counter and performs the
//                    deterministic fixed-order final reduction -> out[0].
//                    All reduction code lives INSIDE this branch (which
//                    returns before the CE path) so the CE path's register
//                    allocation is untouched (round-3 lesson: a common tail
//                    after the if/else join collapsed VGPR 52 -> 6x slower).
//   blocks 1..4096 : one row each -> CE + argmax, single memory pass,
//                    branchless, register-chunked; t==0 epilogue adds only
//                    __threadfence + one atomicAdd (release ticket).
__global__ __launch_bounds__(256, 4) void rt_fused_kernel(
    const float* __restrict__ logits,
    const int*   __restrict__ target,
    const float* __restrict__ rt_in,
    float* __restrict__ ws_rt,
    float* __restrict__ ws_ce,
    float* __restrict__ ws_flag,
    unsigned int* __restrict__ counter,
    float* __restrict__ out)
{
    __shared__ int   hist[4096];
    __shared__ float cand[4][64];
    __shared__ int   ccnt[4];
    __shared__ int   tbin[4], lrank[4];
    __shared__ float quart[4];
    __shared__ int   wsum[4];
    __shared__ float fred[16];
    __shared__ float sm[4], ss[4];
    __shared__ int   si4[4];

    const int t    = threadIdx.x;
    const int lane = t & 63, wv = t >> 6;

    if (blockIdx.x == 0) {
        // ---------- reaction-time transform ----------
        // 1) value histogram (rt uniform in [0,1): bin = floor(x*4096))
        for (int i = t; i < 4096; i += 256) hist[i] = 0;
        __syncthreads();
        for (int i = t; i < 4096; i += 256) {
            float x = rt_in[i];
            int b = (int)(x * 4096.0f);
            b = b < 0 ? 0 : (b > 4095 ? 4095 : b);
            atomicAdd(&hist[b], 1);
        }
        __syncthreads();
        // 2) inclusive scan over the 4096 bins (16 bins/thread + wave scan)
        int base = t * 16;
        int run = 0, loc[16];
        #pragma unroll
        for (int i = 0; i < 16; ++i) { run += hist[base + i]; loc[i] = run; }
        int v = run;
        for (int off = 1; off < 64; off <<= 1) {
            int o = __shfl_up(v, off);
            if (lane >= off) v += o;
        }
        if (lane == 63) wsum[wv] = v;
        __syncthreads();
        int woff = 0;
        for (int w = 0; w < wv; ++w) woff += wsum[w];
        int excl = v - run + woff;          // exclusive prefix for this chunk
        #pragma unroll
        for (int i = 0; i < 16; ++i) hist[base + i] = loc[i] + excl; // inclusive
        if (t < 4) ccnt[t] = 0;
        __syncthreads();
        // 3) locate bins holding ranks 1023,1024,3071,3072 (0-based)
        if (t < 4) {
            const int ranks[4] = {1023, 1024, 3071, 3072};
            int r = ranks[t];
            int lo = 0, hi = 4095;
            while (lo < hi) { int mid = (lo + hi) >> 1; if (hist[mid] >= r + 1) hi = mid; else lo = mid + 1; }
            tbin[t]  = lo;
            lrank[t] = r - (lo ? hist[lo - 1] : 0);
        }
        __syncthreads();
        // 4) collect candidates in those bins
        for (int i = t; i < 4096; i += 256) {
            float x = rt_in[i];
            int b = (int)(x * 4096.0f);
            b = b < 0 ? 0 : (b > 4095 ? 4095 : b);
            #pragma unroll
            for (int k = 0; k < 4; ++k)
                if (b == tbin[k]) {
                    int sl = atomicAdd(&ccnt[k], 1);
                    if (sl < 64) cand[k][sl] = x;
                }
        }
        __syncthreads();
        // 5) lr-th smallest within bin via O(c^2) counting (c ~ Poisson(1))
        if (t < 4) {
            int n  = ccnt[t] < 64 ? ccnt[t] : 64;
            int lr = lrank[t];
            float res = 0.0f;
            for (int i = 0; i < n; ++i) {
                float ci = cand[t][i];
                int lt = 0, le = 0;
                for (int j = 0; j < n; ++j) {
                    float cj = cand[t][j];
                    lt += (cj < ci); le += (cj <= ci);
                }
                if (lt <= lr && lr < le) res = ci;
            }
            quart[t] = res;
        }
        __syncthreads();
        // jnp.quantile linear interp: 0.25*4095=1023.75, 0.75*4095=3071.25
        float lower = quart[0] * 0.25f + quart[1] * 0.75f;
        float upper = quart[2] * 0.75f + quart[3] * 0.25f;
        // 6) clamp tails, interior min/max, normalize
        float mn = 100.0f, mx = -100.0f;   // reference sentinels
        float w16[16];
        #pragma unroll
        for (int c = 0; c < 16; ++c) {
            int i = t + c * 256;
            float x = rt_in[i];
            float w = x < lower ? 0.0f : (x > upper ? 1.0f : x);
            w16[c] = w;
            if (w != 0.0f && w != 1.0f) { mn = fminf(mn, w); mx = fmaxf(mx, w); }
        }
        for (int off = 32; off; off >>= 1) {
            mn = fminf(mn, __shfl_xor(mn, off));
            mx = fmaxf(mx, __shfl_xor(mx, off));
        }
        if (lane == 0) { fred[wv] = mn; fred[8 + wv] = mx; }
        __syncthreads();
        mn = fminf(fminf(fred[0], fred[1]), fminf(fred[2], fred[3]));
        mx = fmaxf(fmaxf(fred[8], fred[9]), fmaxf(fred[10], fred[11]));
        #pragma unroll
        for (int c = 0; c < 16; ++c) {
            int i = t + c * 256;
            float w = w16[c];
            bool interior = (w != 0.0f) && (w != 1.0f);
            ws_rt[i] = interior ? (w - mn) / mx : w;   // reference divides by max
        }

        // ---------- wait for all CE blocks, then deterministic reduce ----
        if (t == 0) {
            while (__hip_atomic_load(counter, __ATOMIC_ACQUIRE,
                                     __HIP_MEMORY_SCOPE_AGENT) < NROWS)
                __builtin_amdgcn_s_sleep(8);
        }
        __syncthreads();
        __threadfence();               // invalidate caches: see other blocks' ws writes
        float a = 0.0f;
        #pragma unroll
        for (int c = 0; c < 16; ++c) {
            int i = t + c * 256;
            a += ws_ce[i] + ws_flag[i] * ws_rt[i];
        }
        float* fs = (float*)hist;      // reuse LDS; barrier above guards reuse
        fs[t] = a;
        __syncthreads();
        for (int off = 128; off; off >>= 1) {
            if (t < off) fs[t] += fs[t + off];
            __syncthreads();
        }
        if (t == 0) out[0] = fs[0] * (1.0f / 4096.0f);
        return;
    }

    // ---------- per-row cross-entropy + argmax, branchless ----------
    const int row = blockIdx.x - 1;
    const float*  rp  = logits + (size_t)row * NCOLS;
    const float4* rp4 = (const float4*)rp;

    float m = -3.0e38f, sum = 0.0f;
    int idx = 0x7fffffff;

    #pragma unroll 1
    for (int ch = 0; ch < 2; ++ch) {
        // batched, unconditional (index-clamped) loads: 16 float4 per thread
        float4 v[16];
        #pragma unroll
        for (int c = 0; c < 16; ++c) {
            int p = t + (ch * 16 + c) * 256;
            int pc = p < NC4 ? p : NC4 - 1;
            v[c] = rp4[pc];
            if (ch == 1 && c == 15) {      // only place p can exceed NC4
                if (p >= NC4) { v[c].x = -3.0e38f; v[c].y = -3.0e38f; v[c].z = -3.0e38f; v[c].w = -3.0e38f; }
            }
        }
        // chunk max + first-index argmax (ascending order, strict >)
        float cm = -3.0e38f; int ci = 0x7fffffff;
        #pragma unroll
        for (int c = 0; c < 16; ++c) {
            int p = t + (ch * 16 + c) * 256;
            float xs[4] = {v[c].x, v[c].y, v[c].z, v[c].w};
            #pragma unroll
            for (int q = 0; q < 4; ++q) {
                bool g = xs[q] > cm;
                cm = g ? xs[q] : cm;
                ci = g ? p * 4 + q : ci;
            }
        }
        float nm = fmaxf(m, cm);
        sum *= __expf(m - nm);             // rescale old partial sum
        if (cm > m) idx = ci;              // tie -> keep earlier chunk's index
        m = nm;
        // independent exp's, 4 partial accumulators (ILP)
        float s0 = 0.0f, s1 = 0.0f, s2 = 0.0f, s3 = 0.0f;
        #pragma unroll
        for (int c = 0; c < 16; ++c) {
            s0 += __expf(v[c].x - nm);
            s1 += __expf(v[c].y - nm);
            s2 += __expf(v[c].z - nm);
            s3 += __expf(v[c].w - nm);
        }
        sum += (s0 + s1) + (s2 + s3);
    }

    // wave combine of (m, sum, idx); tie -> smaller index
    for (int off = 32; off; off >>= 1) {
        float om = __shfl_xor(m, off);
        float os = __shfl_xor(sum, off);
        int   oi = __shfl_xor(idx, off);
        float nm = fmaxf(m, om);
        float ns = sum * __expf(m - nm) + os * __expf(om - nm);
        if (om > m || (om == m && oi < idx)) idx = oi;
        m = nm; sum = ns;
    }
    if (lane == 0) { sm[wv] = m; ss[wv] = sum; si4[wv] = idx; }
    __syncthreads();
    if (t == 0) {
        float M = sm[0], S = ss[0];
        int   I = si4[0];
        for (int w2 = 1; w2 < 4; ++w2) {
            float om = sm[w2], os = ss[w2];
            int   oi = si4[w2];
            float nm = fmaxf(M, om);
            S = S * __expf(M - nm) + os * __expf(om - nm);
            if (om > M || (om == M && oi < I)) I = oi;
            M = nm;
        }
        int tg = target[row];
        float xt = rp[tg];
        ws_ce[row]   = M + logf(S) - xt;          // -log_softmax[target]
        ws_flag[row] = (I != tg) ? 1.0f : 0.0f;   // mispredicted?
        __threadfence();                          // release ws writes
        atomicAdd(counter, 1u);                   // ticket (device scope)
    }
}

extern "C" void kernel_launch(void* const* d_in, const int* in_sizes, int n_in,
                              void* d_out, int out_size, void* d_ws, size_t ws_size,
                              hipStream_t stream) {
    const float* logits = (const float*)d_in[0];
    const int*   target = (const int*)d_in[1];
    const float* rt     = (const float*)d_in[2];

    float* ws_rt   = (float*)d_ws;
    float* ws_ce   = ws_rt + NROWS;
    float* ws_flag = ws_ce + NROWS;
    unsigned int* counter = (unsigned int*)(ws_flag + NROWS);

    hipMemsetAsync(counter, 0, sizeof(unsigned int), stream);
    rt_fused_kernel<<<NROWS + 1, 256, 0, stream>>>(logits, target, rt,
                                                   ws_rt, ws_ce, ws_flag,
                                                   counter, (float*)d_out);
}

// Round 6
// 104.825 us; speedup vs baseline: 2.7338x; 2.7338x over previous
//
#include <hip/hip_runtime.h>
#include <math.h>

#define NROWS 4096
#define NCOLS 32000
#define NC4   8000   // NCOLS / 4
#define CSTRIDE 16   // counter stripe stride in uints (64 B)

// Single fused kernel, 4097 blocks. Cross-block protocol is FENCE-FREE:
// round-5 lesson: __threadfence (device-scope release) on gfx950 emits an
// L2 writeback/invalidate; 4096 of them destroyed L2 residency (98->286us,
// and 616us when all threads fenced). Instead, every cross-block datum
// moves via agent-scope ATOMIC ops (which operate at the coherence point,
// per-address, no cache flush):
//   blocks 1..4096 : CE + argmax (hot loop byte-identical to round 4);
//                    t==0 stores ce/flag with agent-scope atomic stores,
//                    drains vmcnt, bumps a 64-way striped ticket counter.
//   block 0        : rt transform (kept in REGISTERS - row t+c*256 lives in
//                    thread t's w16[c], exactly matching the reduction's
//                    indexing, so no ws_rt array exists at all); spins on
//                    the counter stripes; deterministic fixed-tree reduce.
__global__ __launch_bounds__(256, 4) void rt_fused_kernel(
    const float* __restrict__ logits,
    const int*   __restrict__ target,
    const float* __restrict__ rt_in,
    float* __restrict__ ws_ce,
    float* __restrict__ ws_flag,
    unsigned int* __restrict__ counter,   // 64 stripes, CSTRIDE uints apart
    float* __restrict__ out)
{
    __shared__ int   hist[4096];
    __shared__ float cand[4][64];
    __shared__ int   ccnt[4];
    __shared__ int   tbin[4], lrank[4];
    __shared__ float quart[4];
    __shared__ int   wsum[4];
    __shared__ float fred[16];
    __shared__ float sm[4], ss[4];
    __shared__ int   si4[4];

    const int t    = threadIdx.x;
    const int lane = t & 63, wv = t >> 6;

    if (blockIdx.x == 0) {
        // ---------- reaction-time transform ----------
        for (int i = t; i < 4096; i += 256) hist[i] = 0;
        __syncthreads();
        for (int i = t; i < 4096; i += 256) {
            float x = rt_in[i];
            int b = (int)(x * 4096.0f);
            b = b < 0 ? 0 : (b > 4095 ? 4095 : b);
            atomicAdd(&hist[b], 1);
        }
        __syncthreads();
        // inclusive scan over 4096 bins (16 bins/thread + wave scan)
        int base = t * 16;
        int run = 0, loc[16];
        #pragma unroll
        for (int i = 0; i < 16; ++i) { run += hist[base + i]; loc[i] = run; }
        int v = run;
        for (int off = 1; off < 64; off <<= 1) {
            int o = __shfl_up(v, off);
            if (lane >= off) v += o;
        }
        if (lane == 63) wsum[wv] = v;
        __syncthreads();
        int woff = 0;
        for (int w = 0; w < wv; ++w) woff += wsum[w];
        int excl = v - run + woff;
        #pragma unroll
        for (int i = 0; i < 16; ++i) hist[base + i] = loc[i] + excl;
        if (t < 4) ccnt[t] = 0;
        __syncthreads();
        // locate bins holding ranks 1023,1024,3071,3072
        if (t < 4) {
            const int ranks[4] = {1023, 1024, 3071, 3072};
            int r = ranks[t];
            int lo = 0, hi = 4095;
            while (lo < hi) { int mid = (lo + hi) >> 1; if (hist[mid] >= r + 1) hi = mid; else lo = mid + 1; }
            tbin[t]  = lo;
            lrank[t] = r - (lo ? hist[lo - 1] : 0);
        }
        __syncthreads();
        // collect candidates in those bins
        for (int i = t; i < 4096; i += 256) {
            float x = rt_in[i];
            int b = (int)(x * 4096.0f);
            b = b < 0 ? 0 : (b > 4095 ? 4095 : b);
            #pragma unroll
            for (int k = 0; k < 4; ++k)
                if (b == tbin[k]) {
                    int sl = atomicAdd(&ccnt[k], 1);
                    if (sl < 64) cand[k][sl] = x;
                }
        }
        __syncthreads();
        // lr-th smallest within bin via O(c^2) counting
        if (t < 4) {
            int n  = ccnt[t] < 64 ? ccnt[t] : 64;
            int lr = lrank[t];
            float res = 0.0f;
            for (int i = 0; i < n; ++i) {
                float ci = cand[t][i];
                int lt = 0, le = 0;
                for (int j = 0; j < n; ++j) {
                    float cj = cand[t][j];
                    lt += (cj < ci); le += (cj <= ci);
                }
                if (lt <= lr && lr < le) res = ci;
            }
            quart[t] = res;
        }
        __syncthreads();
        // jnp.quantile linear interp: 0.25*4095=1023.75, 0.75*4095=3071.25
        float lower = quart[0] * 0.25f + quart[1] * 0.75f;
        float upper = quart[2] * 0.75f + quart[3] * 0.25f;
        // clamp tails, interior min/max, normalize -- ALL IN REGISTERS
        float mn = 100.0f, mx = -100.0f;
        float w16[16];
        #pragma unroll
        for (int c = 0; c < 16; ++c) {
            int i = t + c * 256;
            float x = rt_in[i];
            float w = x < lower ? 0.0f : (x > upper ? 1.0f : x);
            w16[c] = w;
            if (w != 0.0f && w != 1.0f) { mn = fminf(mn, w); mx = fmaxf(mx, w); }
        }
        for (int off = 32; off; off >>= 1) {
            mn = fminf(mn, __shfl_xor(mn, off));
            mx = fmaxf(mx, __shfl_xor(mx, off));
        }
        if (lane == 0) { fred[wv] = mn; fred[8 + wv] = mx; }
        __syncthreads();
        mn = fminf(fminf(fred[0], fred[1]), fminf(fred[2], fred[3]));
        mx = fmaxf(fmaxf(fred[8], fred[9]), fmaxf(fred[10], fred[11]));
        #pragma unroll
        for (int c = 0; c < 16; ++c) {
            float w = w16[c];
            bool interior = (w != 0.0f) && (w != 1.0f);
            w16[c] = interior ? (w - mn) / mx : w;   // reference divides by max
        }

        // ---------- spin-wait on striped ticket counter (wave 0) ----------
        if (t < 64) {
            unsigned tot;
            do {
                unsigned c = __hip_atomic_load(&counter[t * CSTRIDE],
                                               __ATOMIC_RELAXED,
                                               __HIP_MEMORY_SCOPE_AGENT);
                tot = c;
                for (int off = 32; off; off >>= 1) tot += __shfl_xor(tot, off);
                if (tot < NROWS) __builtin_amdgcn_s_sleep(2);
            } while (tot < NROWS);
        }
        __syncthreads();

        // ---------- deterministic fixed-tree reduction ----------
        float a = 0.0f;
        #pragma unroll
        for (int c = 0; c < 16; ++c) {
            int i = t + c * 256;
            float ce = __hip_atomic_load(&ws_ce[i],  __ATOMIC_RELAXED,
                                         __HIP_MEMORY_SCOPE_AGENT);
            float fl = __hip_atomic_load(&ws_flag[i], __ATOMIC_RELAXED,
                                         __HIP_MEMORY_SCOPE_AGENT);
            a += ce + fl * w16[c];     // w16[c] IS rt_transformed[i]
        }
        float* fs = (float*)hist;      // reuse LDS; __syncthreads above guards
        fs[t] = a;
        __syncthreads();
        for (int off = 128; off; off >>= 1) {
            if (t < off) fs[t] += fs[t + off];
            __syncthreads();
        }
        if (t == 0) out[0] = fs[0] * (1.0f / 4096.0f);
        return;
    }

    // ---------- per-row cross-entropy + argmax, branchless ----------
    const int row = blockIdx.x - 1;
    const float*  rp  = logits + (size_t)row * NCOLS;
    const float4* rp4 = (const float4*)rp;

    float m = -3.0e38f, sum = 0.0f;
    int idx = 0x7fffffff;

    #pragma unroll 1
    for (int ch = 0; ch < 2; ++ch) {
        // batched, unconditional (index-clamped) loads: 16 float4 per thread
        float4 v[16];
        #pragma unroll
        for (int c = 0; c < 16; ++c) {
            int p = t + (ch * 16 + c) * 256;
            int pc = p < NC4 ? p : NC4 - 1;
            v[c] = rp4[pc];
            if (ch == 1 && c == 15) {      // only place p can exceed NC4
                if (p >= NC4) { v[c].x = -3.0e38f; v[c].y = -3.0e38f; v[c].z = -3.0e38f; v[c].w = -3.0e38f; }
            }
        }
        // chunk max + first-index argmax (ascending order, strict >)
        float cm = -3.0e38f; int ci = 0x7fffffff;
        #pragma unroll
        for (int c = 0; c < 16; ++c) {
            int p = t + (ch * 16 + c) * 256;
            float xs[4] = {v[c].x, v[c].y, v[c].z, v[c].w};
            #pragma unroll
            for (int q = 0; q < 4; ++q) {
                bool g = xs[q] > cm;
                cm = g ? xs[q] : cm;
                ci = g ? p * 4 + q : ci;
            }
        }
        float nm = fmaxf(m, cm);
        sum *= __expf(m - nm);             // rescale old partial sum
        if (cm > m) idx = ci;              // tie -> keep earlier chunk's index
        m = nm;
        // independent exp's, 4 partial accumulators (ILP)
        float s0 = 0.0f, s1 = 0.0f, s2 = 0.0f, s3 = 0.0f;
        #pragma unroll
        for (int c = 0; c < 16; ++c) {
            s0 += __expf(v[c].x - nm);
            s1 += __expf(v[c].y - nm);
            s2 += __expf(v[c].z - nm);
            s3 += __expf(v[c].w - nm);
        }
        sum += (s0 + s1) + (s2 + s3);
    }

    // wave combine of (m, sum, idx); tie -> smaller index
    for (int off = 32; off; off >>= 1) {
        float om = __shfl_xor(m, off);
        float os = __shfl_xor(sum, off);
        int   oi = __shfl_xor(idx, off);
        float nm = fmaxf(m, om);
        float ns = sum * __expf(m - nm) + os * __expf(om - nm);
        if (om > m || (om == m && oi < idx)) idx = oi;
        m = nm; sum = ns;
    }
    if (lane == 0) { sm[wv] = m; ss[wv] = sum; si4[wv] = idx; }
    __syncthreads();
    if (t == 0) {
        float M = sm[0], S = ss[0];
        int   I = si4[0];
        for (int w2 = 1; w2 < 4; ++w2) {
            float om = sm[w2], os = ss[w2];
            int   oi = si4[w2];
            float nm = fmaxf(M, om);
            S = S * __expf(M - nm) + os * __expf(om - nm);
            if (om > M || (om == M && oi < I)) I = oi;
            M = nm;
        }
        int tg = target[row];
        float xt = rp[tg];
        float ce = M + logf(S) - xt;              // -log_softmax[target]
        float fl = (I != tg) ? 1.0f : 0.0f;       // mispredicted?
        // fence-free publication: agent-scope atomic stores (write-through,
        // per-address, no L2 flush), drain, then striped ticket.
        __hip_atomic_store(&ws_ce[row],  ce, __ATOMIC_RELAXED,
                           __HIP_MEMORY_SCOPE_AGENT);
        __hip_atomic_store(&ws_flag[row], fl, __ATOMIC_RELAXED,
                           __HIP_MEMORY_SCOPE_AGENT);
        asm volatile("s_waitcnt vmcnt(0)" ::: "memory");
        __hip_atomic_fetch_add(&counter[(row & 63) * CSTRIDE], 1u,
                               __ATOMIC_RELAXED, __HIP_MEMORY_SCOPE_AGENT);
    }
}

extern "C" void kernel_launch(void* const* d_in, const int* in_sizes, int n_in,
                              void* d_out, int out_size, void* d_ws, size_t ws_size,
                              hipStream_t stream) {
    const float* logits = (const float*)d_in[0];
    const int*   target = (const int*)d_in[1];
    const float* rt     = (const float*)d_in[2];

    float* ws_ce   = (float*)d_ws;
    float* ws_flag = ws_ce + NROWS;
    unsigned int* counter = (unsigned int*)(ws_flag + NROWS);

    hipMemsetAsync(counter, 0, 64 * CSTRIDE * sizeof(unsigned int), stream);
    rt_fused_kernel<<<NROWS + 1, 256, 0, stream>>>(logits, target, rt,
                                                   ws_ce, ws_flag,
                                                   counter, (float*)d_out);
}

// Round 8
// 90.460 us; speedup vs baseline: 3.1679x; 1.1588x over previous
//
#include <hip/hip_runtime.h>
#include <math.h>

#define NROWS 4096
#define NCOLS 32000
#define NC4   8000   // NCOLS / 4

typedef float f4_t __attribute__((ext_vector_type(4)));   // native vec for nt-load

// Block 0:        reaction-time transform via histogram order-statistic
//                 selection (no sort) -> dispatched FIRST, hides under CE.
// Blocks 1..4096: one row each -> CE + argmax, single memory pass,
//                 branchless, register-chunked (2 chunks x 64 floats/thread),
//                 NON-TEMPORAL loads (pure stream, zero reuse -> bypass L1).
// Reduction stays a separate tiny kernel: both fusion attempts (rounds 3,5/6)
// were net-negative (regalloc collapse / fence L2-flush / memset node).
__global__ __launch_bounds__(256, 4) void rt_main_kernel(
    const float* __restrict__ logits,
    const int*   __restrict__ target,
    const float* __restrict__ rt_in,
    float* __restrict__ ws_rt,
    float* __restrict__ ws_ce,
    float* __restrict__ ws_flag)
{
    __shared__ int   hist[4096];
    __shared__ float cand[4][64];
    __shared__ int   ccnt[4];
    __shared__ int   tbin[4], lrank[4];
    __shared__ float quart[4];
    __shared__ int   wsum[4];
    __shared__ float fred[16];
    __shared__ float sm[4], ss[4];
    __shared__ int   si4[4];

    const int t    = threadIdx.x;
    const int lane = t & 63, wv = t >> 6;

    if (blockIdx.x == 0) {
        // ---------- reaction-time transform ----------
        for (int i = t; i < 4096; i += 256) hist[i] = 0;
        __syncthreads();
        for (int i = t; i < 4096; i += 256) {
            float x = rt_in[i];
            int b = (int)(x * 4096.0f);
            b = b < 0 ? 0 : (b > 4095 ? 4095 : b);
            atomicAdd(&hist[b], 1);
        }
        __syncthreads();
        // inclusive scan over 4096 bins (16 bins/thread + wave scan)
        int base = t * 16;
        int run = 0, loc[16];
        #pragma unroll
        for (int i = 0; i < 16; ++i) { run += hist[base + i]; loc[i] = run; }
        int v = run;
        for (int off = 1; off < 64; off <<= 1) {
            int o = __shfl_up(v, off);
            if (lane >= off) v += o;
        }
        if (lane == 63) wsum[wv] = v;
        __syncthreads();
        int woff = 0;
        for (int w = 0; w < wv; ++w) woff += wsum[w];
        int excl = v - run + woff;
        #pragma unroll
        for (int i = 0; i < 16; ++i) hist[base + i] = loc[i] + excl;
        if (t < 4) ccnt[t] = 0;
        __syncthreads();
        // locate bins holding ranks 1023,1024,3071,3072 (0-based)
        if (t < 4) {
            const int ranks[4] = {1023, 1024, 3071, 3072};
            int r = ranks[t];
            int lo = 0, hi = 4095;
            while (lo < hi) { int mid = (lo + hi) >> 1; if (hist[mid] >= r + 1) hi = mid; else lo = mid + 1; }
            tbin[t]  = lo;
            lrank[t] = r - (lo ? hist[lo - 1] : 0);
        }
        __syncthreads();
        // collect candidates in those bins
        for (int i = t; i < 4096; i += 256) {
            float x = rt_in[i];
            int b = (int)(x * 4096.0f);
            b = b < 0 ? 0 : (b > 4095 ? 4095 : b);
            #pragma unroll
            for (int k = 0; k < 4; ++k)
                if (b == tbin[k]) {
                    int sl = atomicAdd(&ccnt[k], 1);
                    if (sl < 64) cand[k][sl] = x;
                }
        }
        __syncthreads();
        // lr-th smallest within bin via O(c^2) counting (c ~ Poisson(1))
        if (t < 4) {
            int n  = ccnt[t] < 64 ? ccnt[t] : 64;
            int lr = lrank[t];
            float res = 0.0f;
            for (int i = 0; i < n; ++i) {
                float ci = cand[t][i];
                int lt = 0, le = 0;
                for (int j = 0; j < n; ++j) {
                    float cj = cand[t][j];
                    lt += (cj < ci); le += (cj <= ci);
                }
                if (lt <= lr && lr < le) res = ci;
            }
            quart[t] = res;
        }
        __syncthreads();
        // jnp.quantile linear interp: 0.25*4095=1023.75, 0.75*4095=3071.25
        float lower = quart[0] * 0.25f + quart[1] * 0.75f;
        float upper = quart[2] * 0.75f + quart[3] * 0.25f;
        // clamp tails, interior min/max, normalize
        float mn = 100.0f, mx = -100.0f;   // reference sentinels
        float w16[16];
        #pragma unroll
        for (int c = 0; c < 16; ++c) {
            int i = t + c * 256;
            float x = rt_in[i];
            float w = x < lower ? 0.0f : (x > upper ? 1.0f : x);
            w16[c] = w;
            if (w != 0.0f && w != 1.0f) { mn = fminf(mn, w); mx = fmaxf(mx, w); }
        }
        for (int off = 32; off; off >>= 1) {
            mn = fminf(mn, __shfl_xor(mn, off));
            mx = fmaxf(mx, __shfl_xor(mx, off));
        }
        if (lane == 0) { fred[wv] = mn; fred[8 + wv] = mx; }
        __syncthreads();
        mn = fminf(fminf(fred[0], fred[1]), fminf(fred[2], fred[3]));
        mx = fmaxf(fmaxf(fred[8], fred[9]), fmaxf(fred[10], fred[11]));
        #pragma unroll
        for (int c = 0; c < 16; ++c) {
            int i = t + c * 256;
            float w = w16[c];
            bool interior = (w != 0.0f) && (w != 1.0f);
            ws_rt[i] = interior ? (w - mn) / mx : w;   // reference divides by max
        }
        return;
    }

    // ---------- per-row cross-entropy + argmax, branchless, nt loads -----
    const int row = blockIdx.x - 1;
    const float* rp  = logits + (size_t)row * NCOLS;
    const f4_t*  rp4 = (const f4_t*)rp;

    float m = -3.0e38f, sum = 0.0f;
    int idx = 0x7fffffff;

    #pragma unroll 1
    for (int ch = 0; ch < 2; ++ch) {
        // batched, unconditional (index-clamped) non-temporal loads
        f4_t v[16];
        #pragma unroll
        for (int c = 0; c < 16; ++c) {
            int p = t + (ch * 16 + c) * 256;
            int pc = p < NC4 ? p : NC4 - 1;
            v[c] = __builtin_nontemporal_load(&rp4[pc]);
            if (ch == 1 && c == 15) {      // only place p can exceed NC4
                if (p >= NC4) { v[c] = (f4_t){-3.0e38f, -3.0e38f, -3.0e38f, -3.0e38f}; }
            }
        }
        // chunk max + first-index argmax (ascending order, strict >)
        float cm = -3.0e38f; int ci = 0x7fffffff;
        #pragma unroll
        for (int c = 0; c < 16; ++c) {
            int p = t + (ch * 16 + c) * 256;
            #pragma unroll
            for (int q = 0; q < 4; ++q) {
                float x = v[c][q];
                bool g = x > cm;
                cm = g ? x : cm;
                ci = g ? p * 4 + q : ci;
            }
        }
        float nm = fmaxf(m, cm);
        sum *= __expf(m - nm);             // rescale old partial sum
        if (cm > m) idx = ci;              // tie -> keep earlier chunk's index
        m = nm;
        // independent exp's, 4 partial accumulators (ILP)
        float s0 = 0.0f, s1 = 0.0f, s2 = 0.0f, s3 = 0.0f;
        #pragma unroll
        for (int c = 0; c < 16; ++c) {
            s0 += __expf(v[c][0] - nm);
            s1 += __expf(v[c][1] - nm);
            s2 += __expf(v[c][2] - nm);
            s3 += __expf(v[c][3] - nm);
        }
        sum += (s0 + s1) + (s2 + s3);
    }

    // wave combine of (m, sum, idx); tie -> smaller index
    for (int off = 32; off; off >>= 1) {
        float om = __shfl_xor(m, off);
        float os = __shfl_xor(sum, off);
        int   oi = __shfl_xor(idx, off);
        float nm = fmaxf(m, om);
        float ns = sum * __expf(m - nm) + os * __expf(om - nm);
        if (om > m || (om == m && oi < idx)) idx = oi;
        m = nm; sum = ns;
    }
    if (lane == 0) { sm[wv] = m; ss[wv] = sum; si4[wv] = idx; }
    __syncthreads();
    if (t == 0) {
        float M = sm[0], S = ss[0];
        int   I = si4[0];
        for (int w2 = 1; w2 < 4; ++w2) {
            float om = sm[w2], os = ss[w2];
            int   oi = si4[w2];
            float nm = fmaxf(M, om);
            S = S * __expf(M - nm) + os * __expf(om - nm);
            if (om > M || (om == M && oi < I)) I = oi;
            M = nm;
        }
        int tg = target[row];
        float xt = rp[tg];
        ws_ce[row]   = M + logf(S) - xt;          // -log_softmax[target]
        ws_flag[row] = (I != tg) ? 1.0f : 0.0f;   // mispredicted?
    }
}

// Deterministic final mean: ce + wrong*rt_transformed, fixed tree order.
// 256 threads, float4 loads (12 KB total input).
__global__ __launch_bounds__(256) void rt_reduce_kernel(
    const float* __restrict__ ws_rt,
    const float* __restrict__ ws_ce,
    const float* __restrict__ ws_flag,
    float* __restrict__ out)
{
    __shared__ float s[256];
    const int t = threadIdx.x;
    const f4_t* rt4 = (const f4_t*)ws_rt;
    const f4_t* ce4 = (const f4_t*)ws_ce;
    const f4_t* fl4 = (const f4_t*)ws_flag;
    float a = 0.0f;
    #pragma unroll
    for (int c = 0; c < 4; ++c) {
        int i = t + c * 256;            // float4 index, 1024 total
        f4_t r = rt4[i], e = ce4[i], f = fl4[i];
        a += (e[0] + f[0] * r[0]) + (e[1] + f[1] * r[1])
           + (e[2] + f[2] * r[2]) + (e[3] + f[3] * r[3]);
    }
    s[t] = a;
    __syncthreads();
    for (int off = 128; off; off >>= 1) {
        if (t < off) s[t] += s[t + off];
        __syncthreads();
    }
    if (t == 0) out[0] = s[0] * (1.0f / 4096.0f);
}

extern "C" void kernel_launch(void* const* d_in, const int* in_sizes, int n_in,
                              void* d_out, int out_size, void* d_ws, size_t ws_size,
                              hipStream_t stream) {
    const float* logits = (const float*)d_in[0];
    const int*   target = (const int*)d_in[1];
    const float* rt     = (const float*)d_in[2];

    float* ws_rt   = (float*)d_ws;
    float* ws_ce   = ws_rt + NROWS;
    float* ws_flag = ws_ce + NROWS;

    rt_main_kernel<<<NROWS + 1, 256, 0, stream>>>(logits, target, rt,
                                                  ws_rt, ws_ce, ws_flag);
    rt_reduce_kernel<<<1, 256, 0, stream>>>(ws_rt, ws_ce, ws_flag, (float*)d_out);
}